// Round 17
// baseline (87.162 us; speedup 1.0000x reference)
//
#include <hip/hip_runtime.h>
#include <math.h>

#define T_SEQ 2048
#define DMODEL 256
#define C_HEAD 64
#define NH 4
#define NWIN 16
#define B_SZ 4

typedef __attribute__((ext_vector_type(8))) short bf16x8;
typedef __attribute__((ext_vector_type(8))) unsigned short ushort8;
typedef __attribute__((ext_vector_type(4))) float f32x4;

#define MFMA(a, b, c) __builtin_amdgcn_mfma_f32_16x16x32_bf16(a, b, c, 0, 0, 0)
// same-wave LDS ordering fence (DS ops of one wave retire in order; this
// guarantees the write data is visible to the following read)
#define FENCE() asm volatile("s_waitcnt lgkmcnt(0)" ::: "memory")

static __device__ __forceinline__ unsigned short f2bf(float f) {
    union { float f; unsigned int u; } v; v.f = f;
    unsigned int r = v.u + 0x7FFFu + ((v.u >> 16) & 1u);
    return (unsigned short)(r >> 16);
}

// ---------------- conv_w: pack weights fragment-major + rope table ------
__global__ __launch_bounds__(256) void conv_w_kernel(
    const float* __restrict__ WQ, const float* __restrict__ WK,
    const float* __restrict__ WV, const float* __restrict__ Wg0,
    const float* __restrict__ Wg1, const float* __restrict__ Wout,
    unsigned short* __restrict__ dst, float2* __restrict__ rtab) {
    const int tid = threadIdx.x;
    if (blockIdx.x >= 72) {
        const float th_tab[8] = {1.f, 0.31622776601683794f, 0.1f,
                                 0.03162277660168379f, 0.01f,
                                 0.0031622776601683794f, 0.001f,
                                 0.00031622776601683794f};
        const int idx = (blockIdx.x - 72) * 256 + tid;   // 0..16383
        const int t = idx >> 3, k = idx & 7;
        const float fr = (float)t * th_tab[k];
        rtab[idx] = make_float2(cosf(fr), sinf(fr));
        return;
    }
    const int i = blockIdx.x * 256 + tid;               // 18432 vec8
    const float* s; long off; long doff;
    if (i < 12288) {                                    // K=256 region
        const long e = (long)i * 8;
        const int col = (int)(e >> 8), k = (int)(e & 255);
        if      (col < 256) { s = WQ; off = (long)col * 256 + k; }
        else if (col < 320) { s = WK; off = (long)(col - 256) * 256 + k; }
        else                { s = WV; off = (long)(col - 320) * 256 + k; }
        doff = ((long)(col >> 4) * 8 + (k >> 5)) * 512 + ((k >> 3) & 3) * 128 + (col & 15) * 8;
    } else {                                            // K=128 region
        const long e = (long)(i - 12288) * 8;
        const int col = (int)(e >> 7), k = (int)(e & 127);
        if      (col < 64)  { s = Wg0; off = (long)col * 128 + k; }
        else if (col < 128) { s = Wg1; off = (long)(col - 64) * 128 + k; }
        else                { s = Wout; off = (long)(col - 128) * 128 + k; }
        doff = 98304 + ((long)(col >> 4) * 4 + (k >> 5)) * 512 + ((k >> 3) & 3) * 128 + (col & 15) * 8;
    }
    const float4* s4 = (const float4*)(s + off);
    float4 a = s4[0], b = s4[1];
    ushort8 o;
    o[0] = f2bf(a.x); o[1] = f2bf(a.y); o[2] = f2bf(a.z); o[3] = f2bf(a.w);
    o[4] = f2bf(b.x); o[5] = f2bf(b.y); o[6] = f2bf(b.z); o[7] = f2bf(b.w);
    *(ushort8*)(dst + doff) = o;
}

// ---------------- fused kernel: ZERO-BARRIER, one wave = one tile -------
// grid = B*(T/16) = 512 blocks x 64 thr (1 wave). Each wave computes its
// 16-token tile end-to-end: H->regs (f32->bf16), K/V GEMM (2 row-tiles),
// Q GEMM (4 heads), attention (4 heads), gates, out. All intermediate
// relayouts go through WAVE-PRIVATE LDS; no __syncthreads anywhere.
__global__ __launch_bounds__(64) void fused_kernel(
    const float* __restrict__ H, const unsigned short* __restrict__ Wallb,
    const float* __restrict__ wq, const float* __restrict__ wk,
    const float* __restrict__ wv, const float2* __restrict__ rtab,
    const float* __restrict__ bg0, const float* __restrict__ bg1,
    const float* __restrict__ bout, float* __restrict__ out)
{
    __shared__ __align__(16) char smem[30720];
    char* q_lds = smem;            // 4 heads x [16 tok][128B] swz (8KB)
    char* k_lds = smem + 8192;     // [32][128B] swz (4KB)
    char* v_t   = smem + 12288;    // V^T [64 ch][80B stride] (5KB)
    char* p_att = smem + 17408;    // P relayout buf (1KB)
    char* o_lds = smem + 18432;    // [16][512B] swz (8KB)
    char* p_lds = smem + 26624;    // [16][256B] swz (4KB)

    const int l   = threadIdx.x;   // lane 0..63
    const int blk = blockIdx.x;
    const int b   = blk >> 7;
    const int t0  = (blk & 127) << 4;
    const int g   = l >> 4;
    const int li  = l & 15;
    const int lane16 = l * 8;      // packed-W per-lane elem offset (16B/lane)
    const unsigned short* Wpk2 = Wallb + 98304;

    // rope cos/sin for this lane's 4 token rows and 4 halo rows
    float2 csT[4], csH[4];
    #pragma unroll
    for (int r = 0; r < 4; ++r) {
        csT[r] = rtab[(t0 + g * 4 + r) * 8 + (li >> 1)];
        int tk = t0 - 16 + g * 4 + r; if (tk < 0) tk = 0;
        csH[r] = rtab[tk * 8 + (li >> 1)];
    }

    // ---- H A-fragments: tile0 = halo [t0-16,t0), tile1 = [t0,t0+16) -----
    bf16x8 hA0[8], hA1[8];
    {
        int r0 = t0 - 16 + li; if (r0 < 0) r0 = 0;     // masked later
        const float* p0 = H + ((size_t)b * T_SEQ + r0) * DMODEL + g * 8;
        const float* p1 = H + ((size_t)b * T_SEQ + t0 + li) * DMODEL + g * 8;
        #pragma unroll
        for (int ks = 0; ks < 8; ++ks) {
            float4 a0 = *(const float4*)(p0 + ks * 32);
            float4 c0 = *(const float4*)(p0 + ks * 32 + 4);
            float4 a1 = *(const float4*)(p1 + ks * 32);
            float4 c1 = *(const float4*)(p1 + ks * 32 + 4);
            bf16x8 t0v, t1v;
            t0v[0] = (short)f2bf(a0.x); t0v[1] = (short)f2bf(a0.y);
            t0v[2] = (short)f2bf(a0.z); t0v[3] = (short)f2bf(a0.w);
            t0v[4] = (short)f2bf(c0.x); t0v[5] = (short)f2bf(c0.y);
            t0v[6] = (short)f2bf(c0.z); t0v[7] = (short)f2bf(c0.w);
            t1v[0] = (short)f2bf(a1.x); t1v[1] = (short)f2bf(a1.y);
            t1v[2] = (short)f2bf(a1.z); t1v[3] = (short)f2bf(a1.w);
            t1v[4] = (short)f2bf(c1.x); t1v[5] = (short)f2bf(c1.y);
            t1v[6] = (short)f2bf(c1.z); t1v[7] = (short)f2bf(c1.w);
            hA0[ks] = t0v;
            hA1[ks] = t1v;
        }
    }

    // ---- K and V GEMMs (both row-tiles) + epilogues ---------------------
    #pragma unroll
    for (int sel = 0; sel < 2; ++sel) {                // 0 = K, 1 = V
        f32x4 acc[2][4] = {};
        #pragma unroll
        for (int ks = 0; ks < 8; ++ks) {
            #pragma unroll
            for (int nf = 0; nf < 4; ++nf) {
                bf16x8 wf = *(const bf16x8*)(Wallb + (size_t)((16 + sel * 4 + nf) * 8 + ks) * 512 + lane16);
                acc[0][nf] = MFMA(hA0[ks], wf, acc[0][nf]);
                acc[1][nf] = MFMA(hA1[ks], wf, acc[1][nf]);
            }
        }
        float gw[4];
        #pragma unroll
        for (int nf = 0; nf < 4; ++nf)
            gw[nf] = (sel == 0) ? wk[nf * 16 + li] : wv[nf * 16 + li];
        #pragma unroll
        for (int tt = 0; tt < 2; ++tt) {
            #pragma unroll
            for (int r = 0; r < 4; ++r) {
                float x0 = acc[tt][0][r], x1 = acc[tt][1][r];
                float x2 = acc[tt][2][r], x3 = acc[tt][3][r];
                float ss = x0 * x0 + x1 * x1 + x2 * x2 + x3 * x3;
                ss += __shfl_xor(ss, 1);
                ss += __shfl_xor(ss, 2);
                ss += __shfl_xor(ss, 4);
                ss += __shfl_xor(ss, 8);
                const float rinv = rsqrtf(ss * (1.0f / 64.0f) + 1e-8f);
                const int row = tt * 16 + g * 4 + r;   // 0..31
                float v0 = x0 * rinv * gw[0];
                float v1 = x1 * rinv * gw[1];
                float v2 = x2 * rinv * gw[2];
                float v3 = x3 * rinv * gw[3];
                float2 cs = tt ? csT[r] : csH[r];
                float px = __shfl_xor(v3, 1);
                v3 = ((li & 1) == 0) ? (v3 * cs.x - px * cs.y) : (px * cs.y + v3 * cs.x);
                if (sel == 0) {
                    const int sw = (row & 7) << 4;
                    *(unsigned short*)(k_lds + ((row * 128 + (0 * 16 + li) * 2) ^ sw)) = f2bf(v0);
                    *(unsigned short*)(k_lds + ((row * 128 + (1 * 16 + li) * 2) ^ sw)) = f2bf(v1);
                    *(unsigned short*)(k_lds + ((row * 128 + (2 * 16 + li) * 2) ^ sw)) = f2bf(v2);
                    *(unsigned short*)(k_lds + ((row * 128 + (3 * 16 + li) * 2) ^ sw)) = f2bf(v3);
                } else {
                    *(unsigned short*)(v_t + (0 * 16 + li) * 80 + row * 2) = f2bf(v0);
                    *(unsigned short*)(v_t + (1 * 16 + li) * 80 + row * 2) = f2bf(v1);
                    *(unsigned short*)(v_t + (2 * 16 + li) * 80 + row * 2) = f2bf(v2);
                    *(unsigned short*)(v_t + (3 * 16 + li) * 80 + row * 2) = f2bf(v3);
                }
            }
        }
    }

    // ---- Q GEMMs (4 heads, token tile only) + epilogues -----------------
    #pragma unroll
    for (int hh = 0; hh < 4; ++hh) {
        f32x4 acc[4] = {};
        #pragma unroll
        for (int ks = 0; ks < 8; ++ks) {
            #pragma unroll
            for (int nf = 0; nf < 4; ++nf) {
                bf16x8 wf = *(const bf16x8*)(Wallb + (size_t)((hh * 4 + nf) * 8 + ks) * 512 + lane16);
                acc[nf] = MFMA(hA1[ks], wf, acc[nf]);
            }
        }
        float gw[4];
        #pragma unroll
        for (int nf = 0; nf < 4; ++nf) gw[nf] = wq[hh * 64 + nf * 16 + li];
        char* qb = q_lds + hh * 2048;
        #pragma unroll
        for (int r = 0; r < 4; ++r) {
            float x0 = acc[0][r], x1 = acc[1][r];
            float x2 = acc[2][r], x3 = acc[3][r];
            float ss = x0 * x0 + x1 * x1 + x2 * x2 + x3 * x3;
            ss += __shfl_xor(ss, 1);
            ss += __shfl_xor(ss, 2);
            ss += __shfl_xor(ss, 4);
            ss += __shfl_xor(ss, 8);
            const float rinv = rsqrtf(ss * (1.0f / 64.0f) + 1e-8f);
            const int tok = g * 4 + r;
            float v0 = x0 * rinv * gw[0];
            float v1 = x1 * rinv * gw[1];
            float v2 = x2 * rinv * gw[2];
            float v3 = x3 * rinv * gw[3];
            float2 cs = csT[r];
            float px = __shfl_xor(v3, 1);
            v3 = ((li & 1) == 0) ? (v3 * cs.x - px * cs.y) : (px * cs.y + v3 * cs.x);
            const int sw = (tok & 7) << 4;
            *(unsigned short*)(qb + ((tok * 128 + (0 * 16 + li) * 2) ^ sw)) = f2bf(v0);
            *(unsigned short*)(qb + ((tok * 128 + (1 * 16 + li) * 2) ^ sw)) = f2bf(v1);
            *(unsigned short*)(qb + ((tok * 128 + (2 * 16 + li) * 2) ^ sw)) = f2bf(v2);
            *(unsigned short*)(qb + ((tok * 128 + (3 * 16 + li) * 2) ^ sw)) = f2bf(v3);
        }
    }
    FENCE();

    // ---- attention: K frags + V frags loaded once; loop over 4 heads ----
    bf16x8 kf[2][2], vf[4];
    #pragma unroll
    for (int tile = 0; tile < 2; ++tile) {
        const int row = tile * 16 + li;
        const int sw = (row & 7) << 4;
        kf[tile][0] = *(const bf16x8*)(k_lds + ((row * 128 + g * 16) ^ sw));
        kf[tile][1] = *(const bf16x8*)(k_lds + ((row * 128 + 64 + g * 16) ^ sw));
    }
    #pragma unroll
    for (int ct = 0; ct < 4; ++ct)
        vf[ct] = *(const bf16x8*)(v_t + (ct * 16 + li) * 80 + g * 16);

    #pragma unroll
    for (int hh = 0; hh < 4; ++hh) {
        const char* qb = q_lds + hh * 2048;
        const int swq = (li & 7) << 4;
        bf16x8 qf0 = *(const bf16x8*)(qb + ((li * 128 + g * 16) ^ swq));
        bf16x8 qf1 = *(const bf16x8*)(qb + ((li * 128 + 64 + g * 16) ^ swq));
        f32x4 st[2];
        #pragma unroll
        for (int tile = 0; tile < 2; ++tile) {
            f32x4 sa = {};
            sa = MFMA(kf[tile][0], qf0, sa);
            sa = MFMA(kf[tile][1], qf1, sa);
            st[tile] = sa;
        }

        float p[8];
        float mx = -1e30f;
        #pragma unroll
        for (int tile = 0; tile < 2; ++tile) {
            #pragma unroll
            for (int r = 0; r < 4; ++r) {
                int krel = tile * 16 - 16 + g * 4 + r;
                int dd = li - krel;
                bool ok = ((unsigned)dd < 16u) && (t0 + krel >= 0);
                float v = ok ? st[tile][r] * 0.125f : -1e30f;
                p[tile * 4 + r] = v;
                mx = fmaxf(mx, v);
            }
        }
        mx = fmaxf(mx, __shfl_xor(mx, 16));
        mx = fmaxf(mx, __shfl_xor(mx, 32));
        float sum = 0.f;
        #pragma unroll
        for (int i = 0; i < 8; ++i) { p[i] = __expf(p[i] - mx); sum += p[i]; }
        sum += __shfl_xor(sum, 16);
        sum += __shfl_xor(sum, 32);
        const float inv = 1.0f / sum;

        // P relayout via wave-private LDS (reused across heads; same-wave
        // DS ops are in-order so WAR across iterations is safe)
        bf16x8 paf;
        {
            uint2 w0, w1;
            w0.x = (unsigned)f2bf(p[0] * inv) | ((unsigned)f2bf(p[1] * inv) << 16);
            w0.y = (unsigned)f2bf(p[2] * inv) | ((unsigned)f2bf(p[3] * inv) << 16);
            w1.x = (unsigned)f2bf(p[4] * inv) | ((unsigned)f2bf(p[5] * inv) << 16);
            w1.y = (unsigned)f2bf(p[6] * inv) | ((unsigned)f2bf(p[7] * inv) << 16);
            const int sw = (li & 3) << 4;
            *(uint2*)(p_att + ((li * 64 + 0 * 32 + g * 8) ^ sw)) = w0;
            *(uint2*)(p_att + ((li * 64 + 1 * 32 + g * 8) ^ sw)) = w1;
            FENCE();
            paf = *(const bf16x8*)(p_att + ((li * 64 + g * 16) ^ sw));
        }

        // PV
        f32x4 o[4] = {};
        #pragma unroll
        for (int ct = 0; ct < 4; ++ct)
            o[ct] = MFMA(paf, vf[ct], o[ct]);

        // inverse rope on chans 48..63; write O tile columns hh*64..
        #pragma unroll
        for (int r = 0; r < 4; ++r) {
            const int row = g * 4 + r;
            float o3 = o[3][r];
            float po = __shfl_xor(o3, 1);
            float2 cs = csT[r];
            o3 = ((li & 1) == 0) ? (o3 * cs.x + po * cs.y) : (-po * cs.y + o3 * cs.x);
            #pragma unroll
            for (int ct = 0; ct < 4; ++ct) {
                const int col = hh * 64 + ct * 16 + li;
                int byte = row * 512 + col * 2;
                byte ^= (row & 7) << 4;
                float val = (ct == 3) ? o3 : o[ct][r];
                *(unsigned short*)(o_lds + byte) = f2bf(val);
            }
        }
    }
    FENCE();

    // ---- gates: 8 colblks (Wg0 cols 0..63 = cb 0..3, Wg1 = cb 4..7) -----
    #pragma unroll
    for (int cq = 0; cq < 8; ++cq) {
        const int gate = cq >> 2;
        f32x4 accp = {};
        #pragma unroll
        for (int ks = 0; ks < 4; ++ks) {
            int byte = li * 512 + (gate * 128 + ks * 32 + g * 8) * 2;
            byte ^= (li & 7) << 4;
            bf16x8 a = *(const bf16x8*)(o_lds + byte);
            bf16x8 wf = *(const bf16x8*)(Wpk2 + (size_t)(cq * 4 + ks) * 512 + lane16);
            accp = MFMA(a, wf, accp);
        }
        const int cl = (cq & 3) * 16 + li;
        const int pcol = gate * 64 + cl;
        const float bb = gate ? bg1[cl] : bg0[cl];
        #pragma unroll
        for (int r = 0; r < 4; ++r) {
            const int row = g * 4 + r;
            int byte = row * 256 + pcol * 2;
            byte ^= (row & 7) << 4;
            *(unsigned short*)(p_lds + byte) = f2bf(accp[r] + bb);
        }
    }
    FENCE();

    // ---- out projection: 16 colblks, K = 128 ----------------------------
    #pragma unroll
    for (int cb = 0; cb < 16; ++cb) {
        f32x4 acco = {};
        #pragma unroll
        for (int ks = 0; ks < 4; ++ks) {
            int byte = li * 256 + (ks * 32 + g * 8) * 2;
            byte ^= (li & 7) << 4;
            bf16x8 a = *(const bf16x8*)(p_lds + byte);
            bf16x8 wf = *(const bf16x8*)(Wpk2 + (size_t)((8 + cb) * 4 + ks) * 512 + lane16);
            acco = MFMA(a, wf, acco);
        }
        const int col = cb * 16 + li;
        const float bb = bout[col];
        #pragma unroll
        for (int r = 0; r < 4; ++r) {
            const int row = g * 4 + r;
            out[(size_t)(b * T_SEQ + t0 + row) * DMODEL + col] = acco[r] + bb;
        }
    }
}

extern "C" void kernel_launch(void* const* d_in, const int* in_sizes, int n_in,
                              void* d_out, int out_size, void* d_ws, size_t ws_size,
                              hipStream_t stream) {
    const float* H    = (const float*)d_in[0];
    const float* WQ   = (const float*)d_in[1];
    const float* WK   = (const float*)d_in[2];
    const float* WV   = (const float*)d_in[3];
    const float* wq   = (const float*)d_in[4];
    const float* wk   = (const float*)d_in[5];
    const float* wv   = (const float*)d_in[6];
    const float* Wg0  = (const float*)d_in[7];
    const float* bg0  = (const float*)d_in[8];
    const float* Wg1  = (const float*)d_in[9];
    const float* bg1  = (const float*)d_in[10];
    const float* Wout = (const float*)d_in[11];
    const float* bout = (const float*)d_in[12];
    float* out = (float*)d_out;

    char* ws = (char*)d_ws;
    unsigned short* Wallb = (unsigned short*)ws;          // 294,912 B
    float2* rtab = (float2*)(ws + 294912);                // 131,072 B

    conv_w_kernel<<<136, 256, 0, stream>>>(WQ, WK, WV, Wg0, Wg1, Wout, Wallb, rtab);
    fused_kernel<<<B_SZ * T_SEQ / 16, 64, 0, stream>>>(H, Wallb, wq, wk, wv, rtab,
                                                       bg0, bg1, bout, out);
}

// Round 18
// 21.043 us; speedup vs baseline: 4.1422x; 4.1422x over previous
//
#include <hip/hip_runtime.h>
#include <math.h>

#define T_SEQ 2048
#define DMODEL 256
#define C_HEAD 64
#define NH 4
#define NWIN 16
#define B_SZ 4

typedef __attribute__((ext_vector_type(8))) short bf16x8;
typedef __attribute__((ext_vector_type(8))) unsigned short ushort8;
typedef __attribute__((ext_vector_type(4))) float f32x4;

// barrier WITHOUT vmcnt drain: cross-wave comm is LDS-only, so only
// lgkmcnt(0) is required; in-flight global (weight-prefetch) loads survive.
#define BAR() asm volatile("s_waitcnt lgkmcnt(0)\n\ts_barrier" ::: "memory")

static __device__ __forceinline__ unsigned short f2bf(float f) {
    union { float f; unsigned int u; } v; v.f = f;
    unsigned int r = v.u + 0x7FFFu + ((v.u >> 16) & 1u);
    return (unsigned short)(r >> 16);
}

// ---------------- conv_w: pack weights fragment-major + rope table ------
__global__ __launch_bounds__(256) void conv_w_kernel(
    const float* __restrict__ WQ, const float* __restrict__ WK,
    const float* __restrict__ WV, const float* __restrict__ Wg0,
    const float* __restrict__ Wg1, const float* __restrict__ Wout,
    unsigned short* __restrict__ dst, float2* __restrict__ rtab) {
    const int tid = threadIdx.x;
    if (blockIdx.x >= 72) {
        // theta[k] = 10000^(-k/8) = 10^(-k/2), compile-time constants
        const float th_tab[8] = {1.f, 0.31622776601683794f, 0.1f,
                                 0.03162277660168379f, 0.01f,
                                 0.0031622776601683794f, 0.001f,
                                 0.00031622776601683794f};
        const int idx = (blockIdx.x - 72) * 256 + tid;   // 0..16383
        const int t = idx >> 3, k = idx & 7;
        const float fr = (float)t * th_tab[k];
        rtab[idx] = make_float2(cosf(fr), sinf(fr));
        return;
    }
    const int i = blockIdx.x * 256 + tid;               // 18432 vec8
    const float* s; long off; long doff;
    if (i < 12288) {                                    // K=256 region
        const long e = (long)i * 8;
        const int col = (int)(e >> 8), k = (int)(e & 255);
        if      (col < 256) { s = WQ; off = (long)col * 256 + k; }
        else if (col < 320) { s = WK; off = (long)(col - 256) * 256 + k; }
        else                { s = WV; off = (long)(col - 320) * 256 + k; }
        doff = ((long)(col >> 4) * 8 + (k >> 5)) * 512 + ((k >> 3) & 3) * 128 + (col & 15) * 8;
    } else {                                            // K=128 region
        const long e = (long)(i - 12288) * 8;
        const int col = (int)(e >> 7), k = (int)(e & 127);
        if      (col < 64)  { s = Wg0; off = (long)col * 128 + k; }
        else if (col < 128) { s = Wg1; off = (long)(col - 64) * 128 + k; }
        else                { s = Wout; off = (long)(col - 128) * 128 + k; }
        doff = 98304 + ((long)(col >> 4) * 4 + (k >> 5)) * 512 + ((k >> 3) & 3) * 128 + (col & 15) * 8;
    }
    const float4* s4 = (const float4*)(s + off);
    float4 a = s4[0], b = s4[1];
    ushort8 o;
    o[0] = f2bf(a.x); o[1] = f2bf(a.y); o[2] = f2bf(a.z); o[3] = f2bf(a.w);
    o[4] = f2bf(b.x); o[5] = f2bf(b.y); o[6] = f2bf(b.z); o[7] = f2bf(b.w);
    *(ushort8*)(dst + doff) = o;
}

// ---------------- fused kernel, BM=32, 16 waves, counted barriers -------
// grid = B*(T/32) = 256 blocks, 1024 thr (16 waves/CU, VGPR-capped max).
// QKV: waves 0-7 = Q (head=w>>1, tok-half=w&1); waves 8-13 = K/V 16-row
// slabs; waves 14-15 prefetch gates weights. Weight fragments prefetched
// before every barrier (barriers don't drain vmcnt).
__global__ __launch_bounds__(1024) void fused_kernel(
    const float* __restrict__ H, const unsigned short* __restrict__ Wallb,
    const float* __restrict__ wq, const float* __restrict__ wk,
    const float* __restrict__ wv, const float2* __restrict__ rtab,
    const float* __restrict__ bg0, const float* __restrict__ bg1,
    const float* __restrict__ bout, float* __restrict__ out)
{
    __shared__ __align__(16) char smem[62464];
    char* lds_a = smem;            // [48][512B] H staging (24KB)   [phase A]
    char* o_lds = smem;            // [32][512B] O tile (16KB)      [reuse]
    char* p_lds = smem + 16384;    // [32][256B] p tile (8KB)       [reuse]
    char* q_lds = smem + 24576;    // 4 heads x [32][128B] (16KB)
    char* k_lds = smem + 40960;    // [48][128B] (6KB)
    char* v_t   = smem + 47104;    // V^T [64 ch][112B stride] (7KB)
    char* p_att = smem + 54272;    // 8 Q-waves x 1KB

    const int tid = threadIdx.x;
    const int blk = blockIdx.x;
    const int b  = blk >> 6;
    const int t0 = (blk & 63) << 5;

    const unsigned short* Wpk2 = Wallb + 98304;   // K=128 packed region

    const int w  = tid >> 6;       // wave 0..15
    const int l  = tid & 63;
    const int g  = l >> 4;
    const int li = l & 15;
    const int lane16 = l * 8;      // packed-W per-lane elem offset (16B/lane)

    // qkv geometry
    const int sel  = (w >= 11) ? 1 : 0;            // for waves 8..13
    const int slab = (w >= 11) ? (w - 11) : (w - 8);
    int cb0, rowa;
    if (w < 8)       { cb0 = (w >> 1) * 4; rowa = 16 + (w & 1) * 16 + li; }
    else if (w < 14) { cb0 = 16 + sel * 4; rowa = slab * 16 + li; }
    else             { cb0 = 0;            rowa = li; }

#define WFRAG(nf, ks) (*(const bf16x8*)(Wallb + (size_t)((cb0 + (nf)) * 8 + (ks)) * 512 + lane16))

    const int gate = (w >> 3) & 1, colq = (w >> 1) & 3, rh = w & 1;
    bf16x8 gpre[4];

    // ---- phase 0: stage H rows [t0-16, t0+32) + prefetch qkv W ----------
    for (int idx = tid; idx < 1536; idx += 1024) {
        int row = idx >> 5, ch = idx & 31;
        int t = t0 - 16 + row; if (t < 0) t = 0;       // masked later
        const float4* s4 = (const float4*)(H + ((size_t)b * T_SEQ + t) * DMODEL + ch * 8);
        float4 a = s4[0], c = s4[1];
        ushort8 o;
        o[0] = f2bf(a.x); o[1] = f2bf(a.y); o[2] = f2bf(a.z); o[3] = f2bf(a.w);
        o[4] = f2bf(c.x); o[5] = f2bf(c.y); o[6] = f2bf(c.z); o[7] = f2bf(c.w);
        int byte = row * 512 + ch * 16;
        byte ^= (row & 7) << 4;
        *(ushort8*)(lds_a + byte) = o;
    }
    bf16x8 cur[4], nxt[4];
    if (w < 14) {
        #pragma unroll
        for (int nf = 0; nf < 4; ++nf) { cur[nf] = WFRAG(nf, 0); nxt[nf] = WFRAG(nf, 1); }
    } else {
        // idle waves: prefetch their gates weights now
        #pragma unroll
        for (int ks = 0; ks < 4; ++ks)
            gpre[ks] = *(const bf16x8*)(Wpk2 + (size_t)((gate * 4 + colq) * 4 + ks) * 512 + lane16);
    }
    BAR();

    // ---- phase 1: qkv with 2-deep rolling weight prefetch ---------------
    if (w < 14) {
        f32x4 acc[4] = {};
        #pragma unroll
        for (int ks = 0; ks < 8; ++ks) {
            bf16x8 fut[4];
            if (ks < 6) {
                #pragma unroll
                for (int nf = 0; nf < 4; ++nf) fut[nf] = WFRAG(nf, ks + 2);
            }
            int abyte = rowa * 512 + (ks * 32 + g * 8) * 2;
            abyte ^= (rowa & 7) << 4;
            bf16x8 a = *(const bf16x8*)(lds_a + abyte);
            #pragma unroll
            for (int nf = 0; nf < 4; ++nf)
                acc[nf] = __builtin_amdgcn_mfma_f32_16x16x32_bf16(a, cur[nf], acc[nf], 0, 0, 0);
            #pragma unroll
            for (int nf = 0; nf < 4; ++nf) { cur[nf] = nxt[nf]; nxt[nf] = fut[nf]; }
        }

        if (w < 8) {
            const int h = w >> 1;
            float gw[4];
            #pragma unroll
            for (int nf = 0; nf < 4; ++nf) gw[nf] = wq[h * 64 + nf * 16 + li];
            #pragma unroll
            for (int r = 0; r < 4; ++r) {
                float x0 = acc[0][r], x1 = acc[1][r];
                float x2 = acc[2][r], x3 = acc[3][r];
                float ss = x0 * x0 + x1 * x1 + x2 * x2 + x3 * x3;
                ss += __shfl_xor(ss, 1);
                ss += __shfl_xor(ss, 2);
                ss += __shfl_xor(ss, 4);
                ss += __shfl_xor(ss, 8);
                const float rinv = rsqrtf(ss * (1.0f / 64.0f) + 1e-8f);
                const int tok = (w & 1) * 16 + g * 4 + r;   // 0..31
                const int t = t0 + tok;
                float v0 = x0 * rinv * gw[0];
                float v1 = x1 * rinv * gw[1];
                float v2 = x2 * rinv * gw[2];
                float v3 = x3 * rinv * gw[3];
                float2 cs = rtab[t * 8 + (li >> 1)];
                float px = __shfl_xor(v3, 1);
                v3 = ((li & 1) == 0) ? (v3 * cs.x - px * cs.y) : (px * cs.y + v3 * cs.x);
                char* qb = q_lds + h * 4096;
                const int sw = (tok & 7) << 4;
                *(unsigned short*)(qb + ((tok * 128 + (0 * 16 + li) * 2) ^ sw)) = f2bf(v0);
                *(unsigned short*)(qb + ((tok * 128 + (1 * 16 + li) * 2) ^ sw)) = f2bf(v1);
                *(unsigned short*)(qb + ((tok * 128 + (2 * 16 + li) * 2) ^ sw)) = f2bf(v2);
                *(unsigned short*)(qb + ((tok * 128 + (3 * 16 + li) * 2) ^ sw)) = f2bf(v3);
            }
        } else {
            float gw[4];
            #pragma unroll
            for (int nf = 0; nf < 4; ++nf)
                gw[nf] = (sel == 0) ? wk[nf * 16 + li] : wv[nf * 16 + li];
            #pragma unroll
            for (int r = 0; r < 4; ++r) {
                float x0 = acc[0][r], x1 = acc[1][r];
                float x2 = acc[2][r], x3 = acc[3][r];
                float ss = x0 * x0 + x1 * x1 + x2 * x2 + x3 * x3;
                ss += __shfl_xor(ss, 1);
                ss += __shfl_xor(ss, 2);
                ss += __shfl_xor(ss, 4);
                ss += __shfl_xor(ss, 8);
                const float rinv = rsqrtf(ss * (1.0f / 64.0f) + 1e-8f);
                const int row = slab * 16 + g * 4 + r;     // halo row 0..47
                int tk = t0 - 16 + row; if (tk < 0) tk = 0;
                float v0 = x0 * rinv * gw[0];
                float v1 = x1 * rinv * gw[1];
                float v2 = x2 * rinv * gw[2];
                float v3 = x3 * rinv * gw[3];
                float2 cs = rtab[tk * 8 + (li >> 1)];
                float px = __shfl_xor(v3, 1);
                v3 = ((li & 1) == 0) ? (v3 * cs.x - px * cs.y) : (px * cs.y + v3 * cs.x);
                if (sel == 0) {
                    const int sw = (row & 7) << 4;
                    *(unsigned short*)(k_lds + ((row * 128 + (0 * 16 + li) * 2) ^ sw)) = f2bf(v0);
                    *(unsigned short*)(k_lds + ((row * 128 + (1 * 16 + li) * 2) ^ sw)) = f2bf(v1);
                    *(unsigned short*)(k_lds + ((row * 128 + (2 * 16 + li) * 2) ^ sw)) = f2bf(v2);
                    *(unsigned short*)(k_lds + ((row * 128 + (3 * 16 + li) * 2) ^ sw)) = f2bf(v3);
                } else {
                    *(unsigned short*)(v_t + (0 * 16 + li) * 112 + row * 2) = f2bf(v0);
                    *(unsigned short*)(v_t + (1 * 16 + li) * 112 + row * 2) = f2bf(v1);
                    *(unsigned short*)(v_t + (2 * 16 + li) * 112 + row * 2) = f2bf(v2);
                    *(unsigned short*)(v_t + (3 * 16 + li) * 112 + row * 2) = f2bf(v3);
                }
            }
        }
    }
    BAR();

    // ---- phase 2: attention (waves 0-7); waves 8-13 prefetch gates W ----
    if (w >= 8 && w < 14) {
        #pragma unroll
        for (int ks = 0; ks < 4; ++ks)
            gpre[ks] = *(const bf16x8*)(Wpk2 + (size_t)((gate * 4 + colq) * 4 + ks) * 512 + lane16);
    }
    if (w < 8) {
        const int h  = w >> 1;
        const int th = w & 1;
        bf16x8 qf0, qf1;
        {
            const char* qb = q_lds + h * 4096;
            const int tok = th * 16 + li;
            const int sw = (tok & 7) << 4;
            qf0 = *(const bf16x8*)(qb + ((tok * 128 + g * 16) ^ sw));
            qf1 = *(const bf16x8*)(qb + ((tok * 128 + 64 + g * 16) ^ sw));
        }
        f32x4 st[2];
        #pragma unroll
        for (int tile = 0; tile < 2; ++tile) {
            const int row = th * 16 + tile * 16 + li;  // halo key row
            const int sw = (row & 7) << 4;
            bf16x8 kf0 = *(const bf16x8*)(k_lds + ((row * 128 + g * 16) ^ sw));
            bf16x8 kf1 = *(const bf16x8*)(k_lds + ((row * 128 + 64 + g * 16) ^ sw));
            f32x4 sa = {};
            sa = __builtin_amdgcn_mfma_f32_16x16x32_bf16(kf0, qf0, sa, 0, 0, 0);
            sa = __builtin_amdgcn_mfma_f32_16x16x32_bf16(kf1, qf1, sa, 0, 0, 0);
            st[tile] = sa;
        }

        float p[8];
        float mx = -1e30f;
        #pragma unroll
        for (int tile = 0; tile < 2; ++tile) {
            #pragma unroll
            for (int r = 0; r < 4; ++r) {
                int krel = tile * 16 - 16 + g * 4 + r;    // key - token_base
                int dd = li - krel;                        // token - key
                bool ok = ((unsigned)dd < 16u) && (t0 + th * 16 + krel >= 0);
                float v = ok ? st[tile][r] * 0.125f : -1e30f;
                p[tile * 4 + r] = v;
                mx = fmaxf(mx, v);
            }
        }
        mx = fmaxf(mx, __shfl_xor(mx, 16));
        mx = fmaxf(mx, __shfl_xor(mx, 32));
        float sum = 0.f;
        #pragma unroll
        for (int i = 0; i < 8; ++i) { p[i] = __expf(p[i] - mx); sum += p[i]; }
        sum += __shfl_xor(sum, 16);
        sum += __shfl_xor(sum, 32);
        const float inv = 1.0f / sum;

        // P -> wave-local LDS relayout to K=32 A-fragment
        bf16x8 paf;
        {
            char* pbase = p_att + w * 1024;
            uint2 w0, w1;
            w0.x = (unsigned)f2bf(p[0] * inv) | ((unsigned)f2bf(p[1] * inv) << 16);
            w0.y = (unsigned)f2bf(p[2] * inv) | ((unsigned)f2bf(p[3] * inv) << 16);
            w1.x = (unsigned)f2bf(p[4] * inv) | ((unsigned)f2bf(p[5] * inv) << 16);
            w1.y = (unsigned)f2bf(p[6] * inv) | ((unsigned)f2bf(p[7] * inv) << 16);
            const int sw = (li & 3) << 4;
            *(uint2*)(pbase + ((li * 64 + 0 * 32 + g * 8) ^ sw)) = w0;
            *(uint2*)(pbase + ((li * 64 + 1 * 32 + g * 8) ^ sw)) = w1;
            asm volatile("s_waitcnt lgkmcnt(0)" ::: "memory");
            paf = *(const bf16x8*)(pbase + ((li * 64 + g * 16) ^ sw));
        }

        // PV via V^T: single b128 B-frag per ctile
        f32x4 o[4] = {};
        #pragma unroll
        for (int ctile = 0; ctile < 4; ++ctile) {
            bf16x8 vf = *(const bf16x8*)(v_t + (ctile * 16 + li) * 112 + th * 32 + g * 16);
            o[ctile] = __builtin_amdgcn_mfma_f32_16x16x32_bf16(paf, vf, o[ctile], 0, 0, 0);
        }

        // inverse rope on chans 48..63; write O to swizzled LDS
        #pragma unroll
        for (int r = 0; r < 4; ++r) {
            const int row = th * 16 + g * 4 + r;       // 0..31
            const int t = t0 + row;
            float o3 = o[3][r];
            float po = __shfl_xor(o3, 1);
            float2 cs = rtab[t * 8 + (li >> 1)];
            o3 = ((li & 1) == 0) ? (o3 * cs.x + po * cs.y) : (-po * cs.y + o3 * cs.x);
            #pragma unroll
            for (int ctile = 0; ctile < 4; ++ctile) {
                const int col = h * 64 + ctile * 16 + li;
                int byte = row * 512 + col * 2;
                byte ^= (row & 7) << 4;
                float val = (ctile == 3) ? o3 : o[ctile][r];
                *(unsigned short*)(o_lds + byte) = f2bf(val);
            }
        }
        // prefetch gates weights (after attn compute, before barrier)
        #pragma unroll
        for (int ks = 0; ks < 4; ++ks)
            gpre[ks] = *(const bf16x8*)(Wpk2 + (size_t)((gate * 4 + colq) * 4 + ks) * 512 + lane16);
    }
    BAR();

    // ---- phase 3: gates (prefetched W) + prefetch out W -----------------
    bf16x8 opre[4];
    {
        const float* bg = gate ? bg1 : bg0;
        f32x4 accp = {};
        #pragma unroll
        for (int ks = 0; ks < 4; ++ks) {
            const int row = rh * 16 + li;
            int byte = row * 512 + (gate * 128 + ks * 32 + g * 8) * 2;
            byte ^= (row & 7) << 4;
            bf16x8 a = *(const bf16x8*)(o_lds + byte);
            accp = __builtin_amdgcn_mfma_f32_16x16x32_bf16(a, gpre[ks], accp, 0, 0, 0);
        }
        // prefetch out-projection weights (colblk = 8 + w)
        #pragma unroll
        for (int ks = 0; ks < 4; ++ks)
            opre[ks] = *(const bf16x8*)(Wpk2 + (size_t)((8 + w) * 4 + ks) * 512 + lane16);
        const int cl = colq * 16 + li;
        const int pcol = gate * 64 + cl;
        const float bb = bg[cl];
        #pragma unroll
        for (int r = 0; r < 4; ++r) {
            const int row = rh * 16 + g * 4 + r;
            int byte = row * 256 + pcol * 2;
            byte ^= (row & 7) << 4;
            *(unsigned short*)(p_lds + byte) = f2bf(accp[r] + bb);
        }
    }
    BAR();

    // ---- phase 4: out. wave w -> cols w*16 .. w*16+15, 32 rows ----------
    {
        f32x4 acco[2] = {};
        #pragma unroll
        for (int ks = 0; ks < 4; ++ks) {
            bf16x8 a[2];
            #pragma unroll
            for (int mf = 0; mf < 2; ++mf) {
                const int row = mf * 16 + li;
                int byte = row * 256 + (ks * 32 + g * 8) * 2;
                byte ^= (row & 7) << 4;
                a[mf] = *(const bf16x8*)(p_lds + byte);
            }
            acco[0] = __builtin_amdgcn_mfma_f32_16x16x32_bf16(a[0], opre[ks], acco[0], 0, 0, 0);
            acco[1] = __builtin_amdgcn_mfma_f32_16x16x32_bf16(a[1], opre[ks], acco[1], 0, 0, 0);
        }
        const int col = w * 16 + li;
        const float bb = bout[col];
        #pragma unroll
        for (int mf = 0; mf < 2; ++mf) {
            #pragma unroll
            for (int r = 0; r < 4; ++r) {
                const int row = mf * 16 + g * 4 + r;
                out[(size_t)(b * T_SEQ + t0 + row) * DMODEL + col] = acco[mf][r] + bb;
            }
        }
    }
#undef WFRAG
}

extern "C" void kernel_launch(void* const* d_in, const int* in_sizes, int n_in,
                              void* d_out, int out_size, void* d_ws, size_t ws_size,
                              hipStream_t stream) {
    const float* H    = (const float*)d_in[0];
    const float* WQ   = (const float*)d_in[1];
    const float* WK   = (const float*)d_in[2];
    const float* WV   = (const float*)d_in[3];
    const float* wq   = (const float*)d_in[4];
    const float* wk   = (const float*)d_in[5];
    const float* wv   = (const float*)d_in[6];
    const float* Wg0  = (const float*)d_in[7];
    const float* bg0  = (const float*)d_in[8];
    const float* Wg1  = (const float*)d_in[9];
    const float* bg1  = (const float*)d_in[10];
    const float* Wout = (const float*)d_in[11];
    const float* bout = (const float*)d_in[12];
    float* out = (float*)d_out;

    char* ws = (char*)d_ws;
    unsigned short* Wallb = (unsigned short*)ws;          // 294,912 B
    float2* rtab = (float2*)(ws + 294912);                // 131,072 B

    conv_w_kernel<<<136, 256, 0, stream>>>(WQ, WK, WV, Wg0, Wg1, Wout, Wallb, rtab);
    fused_kernel<<<B_SZ * T_SEQ / 32, 1024, 0, stream>>>(H, Wallb, wq, wk, wv, rtab,
                                                         bg0, bg1, bout, out);
}